// Round 1
// baseline (464.363 us; speedup 1.0000x reference)
//
#include <hip/hip_runtime.h>
#include <hip/hip_bf16.h>

typedef __attribute__((ext_vector_type(8))) short short8;
typedef __attribute__((ext_vector_type(4))) float f32x4;
typedef __attribute__((ext_vector_type(4))) unsigned short u16x4;

#define M_TOT 16384
#define N_TOT 2048
#define K_TOT 2048

__device__ __forceinline__ unsigned short f2bf(float f) {
  unsigned u = __builtin_bit_cast(unsigned, f);
  u += 0x7FFFu + ((u >> 16) & 1u);   // RNE
  return (unsigned short)(u >> 16);
}
__device__ __forceinline__ float bf2f(unsigned short h) {
  return __builtin_bit_cast(float, (unsigned)h << 16);
}

// ---------------- W_eff = W_base + U*diag(S*(v@P))*Vh, split into bf16 hi/lo --
__global__ void wsplit_kernel(const float* __restrict__ Wb, const float* __restrict__ U,
                              const float* __restrict__ S, const float* __restrict__ Vh,
                              const float* __restrict__ P, const float* __restrict__ gv,
                              unsigned short* __restrict__ Whi, unsigned short* __restrict__ Wlo) {
  float c0 = 0.f, c1 = 0.f;
#pragma unroll
  for (int u = 0; u < 16; ++u) { c0 += gv[u] * P[2 * u]; c1 += gv[u] * P[2 * u + 1]; }
  c0 *= S[0]; c1 *= S[1];
  int t = blockIdx.x * 256 + threadIdx.x;      // 1M threads, 4 elems each
  int o = t >> 9;                              // 512 float4 per row of 2048
  int d = (t & 511) << 2;
  f32x4 wb = *(const f32x4*)(Wb + (size_t)o * K_TOT + d);
  f32x4 v0 = *(const f32x4*)(Vh + d);
  f32x4 v1 = *(const f32x4*)(Vh + K_TOT + d);
  float u0 = U[2 * o] * c0, u1 = U[2 * o + 1] * c1;
  u16x4 hi, lo;
#pragma unroll
  for (int q = 0; q < 4; ++q) {
    float w = wb[q] + u0 * v0[q] + u1 * v1[q];
    unsigned short h = f2bf(w);
    hi[q] = h;
    lo[q] = f2bf(w - bf2f(h));
  }
  *(u16x4*)(Whi + (size_t)o * K_TOT + d) = hi;
  *(u16x4*)(Wlo + (size_t)o * K_TOT + d) = lo;
}

// ---------------- split-bf16 GEMM: out[m][n] = sum_k x[m][k]*W[n][k] + bias[n]
// 128x128 tile, BK=32, 4 waves, 16x16x32 bf16 MFMA, 3-product split accumulate.
__global__ __launch_bounds__(256) void gemm_split_kernel(
    const float* __restrict__ X, const unsigned short* __restrict__ Whi,
    const unsigned short* __restrict__ Wlo, const float* __restrict__ bias,
    float* __restrict__ out) {
  __shared__ unsigned short sAhi[128 * 32];
  __shared__ unsigned short sAlo[128 * 32];
  __shared__ unsigned short sBhi[128 * 32];
  __shared__ unsigned short sBlo[128 * 32];

  const int tid = threadIdx.x;
  const int lane = tid & 63;
  const int w = tid >> 6;
  const int wr = w >> 1, wc = w & 1;        // wave -> 64x64 quadrant
  const int r = lane & 15, g = lane >> 4;   // MFMA fragment coords
  const int bn = blockIdx.x, bm = blockIdx.y;

  f32x4 acc[4][4] = {};

  // A staging: thread t loads 4 x float4 (rows t/8 + {0,32,64,96}, col (t&7)*4)
  const int arow = tid >> 3;
  const int acol = (tid & 7) << 2;
  const float* Abase = X + (size_t)(bm * 128 + arow) * K_TOT + acol;

  // B staging via global_load_lds: lane l -> row l/4, col (l&3)*8 within 16-row chunk
  const int brow = lane >> 2;
  const int bcol = (lane & 3) << 3;
  const size_t bgoff = (size_t)(bn * 128 + brow) * K_TOT + bcol;

  for (int kt = 0; kt < K_TOT / 32; ++kt) {
    // prefetch A fp32 into regs (no LDS touch -> can overlap prev compute)
    f32x4 av[4];
#pragma unroll
    for (int p = 0; p < 4; ++p)
      av[p] = *(const f32x4*)(Abase + (size_t)(p * 32) * K_TOT + kt * 32);

    __syncthreads();  // previous tile's reads done

    // B hi/lo tiles: 8KB each; each wave issues 2+2 width-16 global_load_lds
#pragma unroll
    for (int ii = 0; ii < 2; ++ii) {
      int chunk = w * 2 + ii;
      size_t go = bgoff + (size_t)(chunk * 16) * K_TOT + kt * 32;
      __builtin_amdgcn_global_load_lds(
          (const __attribute__((address_space(1))) void*)(Whi + go),
          (__attribute__((address_space(3))) void*)(&sBhi[chunk * 512]), 16, 0, 0);
      __builtin_amdgcn_global_load_lds(
          (const __attribute__((address_space(1))) void*)(Wlo + go),
          (__attribute__((address_space(3))) void*)(&sBlo[chunk * 512]), 16, 0, 0);
    }

    // A: fp32 -> (hi, lo) bf16 split, write to LDS (conflict-free contiguous)
#pragma unroll
    for (int p = 0; p < 4; ++p) {
      u16x4 hi, lo;
#pragma unroll
      for (int q = 0; q < 4; ++q) {
        float f = av[p][q];
        unsigned short h = f2bf(f);
        hi[q] = h;
        lo[q] = f2bf(f - bf2f(h));
      }
      int off = (arow + p * 32) * 32 + acol;
      *(u16x4*)&sAhi[off] = hi;
      *(u16x4*)&sAlo[off] = lo;
    }

    __syncthreads();  // drains vmcnt (B tiles) + lgkmcnt (A writes)

    // fragment loads: each lane reads distinct 16B of a contiguous 1KB row-band
    short8 ah[4], al[4], bh[4], bl[4];
#pragma unroll
    for (int i = 0; i < 4; ++i) {
      int off = (wr * 64 + i * 16 + r) * 32 + g * 8;
      ah[i] = *(const short8*)&sAhi[off];
      al[i] = *(const short8*)&sAlo[off];
    }
#pragma unroll
    for (int j = 0; j < 4; ++j) {
      int off = (wc * 64 + j * 16 + r) * 32 + g * 8;
      bh[j] = *(const short8*)&sBhi[off];
      bl[j] = *(const short8*)&sBlo[off];
    }

#pragma unroll
    for (int i = 0; i < 4; ++i)
#pragma unroll
      for (int j = 0; j < 4; ++j) {
        acc[i][j] = __builtin_amdgcn_mfma_f32_16x16x32_bf16(ah[i], bh[j], acc[i][j], 0, 0, 0);
        acc[i][j] = __builtin_amdgcn_mfma_f32_16x16x32_bf16(ah[i], bl[j], acc[i][j], 0, 0, 0);
        acc[i][j] = __builtin_amdgcn_mfma_f32_16x16x32_bf16(al[i], bh[j], acc[i][j], 0, 0, 0);
      }
  }

  // epilogue: C/D mapping col = lane&15, row = (lane>>4)*4 + reg  [m89-verified]
#pragma unroll
  for (int j = 0; j < 4; ++j) {
    int n = bn * 128 + wc * 64 + j * 16 + r;
    float bv = bias[n];
#pragma unroll
    for (int i = 0; i < 4; ++i) {
      int mbase = bm * 128 + wr * 64 + i * 16 + g * 4;
#pragma unroll
      for (int q = 0; q < 4; ++q) {
        out[(size_t)(mbase + q) * N_TOT + n] = acc[i][j][q] + bv;
      }
    }
  }
}

extern "C" void kernel_launch(void* const* d_in, const int* in_sizes, int n_in,
                              void* d_out, int out_size, void* d_ws, size_t ws_size,
                              hipStream_t stream) {
  const float* x    = (const float*)d_in[0];
  const float* Wb   = (const float*)d_in[1];
  const float* bias = (const float*)d_in[2];
  const float* U    = (const float*)d_in[3];
  const float* S    = (const float*)d_in[4];
  const float* Vh   = (const float*)d_in[5];
  const float* P    = (const float*)d_in[6];
  const float* gv   = (const float*)d_in[7];
  float* out = (float*)d_out;

  // workspace: Whi (8MB) + Wlo (8MB) bf16, row-major [N][K]
  unsigned short* Whi = (unsigned short*)d_ws;
  unsigned short* Wlo = Whi + (size_t)N_TOT * K_TOT;

  wsplit_kernel<<<dim3((N_TOT * K_TOT / 4) / 256), 256, 0, stream>>>(
      Wb, U, S, Vh, P, gv, Whi, Wlo);

  gemm_split_kernel<<<dim3(N_TOT / 128, M_TOT / 128), 256, 0, stream>>>(
      x, Whi, Wlo, bias, out);
}

// Round 2
// 266.298 us; speedup vs baseline: 1.7438x; 1.7438x over previous
//
#include <hip/hip_runtime.h>
#include <hip/hip_bf16.h>

typedef __attribute__((ext_vector_type(8))) short short8;
typedef __attribute__((ext_vector_type(4))) float f32x4;
typedef __attribute__((ext_vector_type(2))) float f32x2;
typedef __attribute__((ext_vector_type(4))) unsigned short u16x4;
typedef __attribute__((ext_vector_type(8))) unsigned short u16x8;

#define M_TOT 16384
#define N_TOT 2048
#define K_TOT 2048

__device__ __forceinline__ unsigned short f2bf(float f) {
  unsigned u = __builtin_bit_cast(unsigned, f);
  u += 0x7FFFu + ((u >> 16) & 1u);   // RNE
  return (unsigned short)(u >> 16);
}
__device__ __forceinline__ float bf2f(unsigned short h) {
  return __builtin_bit_cast(float, (unsigned)h << 16);
}
// XOR swizzle: within a [rows][32-col] bf16 tile, chunk = 16B (8 cols).
// Spreads 8 consecutive rows' same-chunk reads across 8 bank-groups. Bijective.
__device__ __forceinline__ int swz_byte(int row, int chunk) {
  return ((row << 6) + (chunk << 4)) ^ ((row & 7) << 4);
}

// ===================== TILED FAST PATH ======================================
// ws layout: Whi_t[4M ush] Wlo_t[4M ush] Xhi_t[32M ush] T[32768 f32] CU[4096 f32]
// W tiles: [N/128][K/32][128x32 swizzled, 8192 B]
// X tiles: [M/256][K/32][256x32 swizzled, 16384 B]

__global__ void wsplit_tiled(const float* __restrict__ Wb, const float* __restrict__ U,
                             const float* __restrict__ S, const float* __restrict__ Vh,
                             const float* __restrict__ P, const float* __restrict__ gv,
                             unsigned short* __restrict__ Whi_t,
                             unsigned short* __restrict__ Wlo_t,
                             float* __restrict__ CU) {
  float c0 = 0.f, c1 = 0.f;
#pragma unroll
  for (int u = 0; u < 16; ++u) { c0 += gv[u] * P[2 * u]; c1 += gv[u] * P[2 * u + 1]; }
  c0 *= S[0]; c1 *= S[1];
  int t = blockIdx.x * 256 + threadIdx.x;
  int o = t >> 8;            // output row 0..2047
  int c = t & 255;           // 16B chunk (8 cols)
  int k = c << 3;
  f32x4 wb0 = *(const f32x4*)(Wb + (size_t)o * K_TOT + k);
  f32x4 wb1 = *(const f32x4*)(Wb + (size_t)o * K_TOT + k + 4);
  f32x4 v0a = *(const f32x4*)(Vh + k);
  f32x4 v0b = *(const f32x4*)(Vh + k + 4);
  f32x4 v1a = *(const f32x4*)(Vh + K_TOT + k);
  f32x4 v1b = *(const f32x4*)(Vh + K_TOT + k + 4);
  float u0 = U[2 * o] * c0, u1 = U[2 * o + 1] * c1;
  u16x8 hi, lo;
#pragma unroll
  for (int q = 0; q < 4; ++q) {
    float w = wb0[q] + u0 * v0a[q] + u1 * v1a[q];
    unsigned short h = f2bf(w);
    hi[q] = h; lo[q] = f2bf(w - bf2f(h));
  }
#pragma unroll
  for (int q = 0; q < 4; ++q) {
    float w = wb1[q] + u0 * v0b[q] + u1 * v1b[q];
    unsigned short h = f2bf(w);
    hi[4 + q] = h; lo[4 + q] = f2bf(w - bf2f(h));
  }
  size_t tile = (size_t)((o >> 7) * 64 + (c >> 2)) * 8192;  // bytes
  int b = swz_byte(o & 127, c & 3);
  *(u16x8*)((char*)Whi_t + tile + b) = hi;
  *(u16x8*)((char*)Wlo_t + tile + b) = lo;
  if (c == 0) {
    CU[2 * o]     = c0 * U[2 * o];
    CU[2 * o + 1] = c1 * U[2 * o + 1];
  }
}

// x -> bf16 hi (tiled+swizzled) ; t[m][r] = sum_k (x - hi)[m,k] * Vh[r,k]
__global__ void xsplit_tiled(const float* __restrict__ X, const float* __restrict__ Vh,
                             unsigned short* __restrict__ Xhi_t, float* __restrict__ T) {
  int w = threadIdx.x >> 6, lane = threadIdx.x & 63;
  int m = blockIdx.x * 4 + w;
  const float* xr = X + (size_t)m * K_TOT;
  float t0 = 0.f, t1 = 0.f;
#pragma unroll
  for (int p = 0; p < 4; ++p) {
    int c = lane + (p << 6);   // chunk 0..255
    int k = c << 3;
    f32x4 x0 = *(const f32x4*)(xr + k);
    f32x4 x1 = *(const f32x4*)(xr + k + 4);
    f32x4 v0a = *(const f32x4*)(Vh + k);
    f32x4 v0b = *(const f32x4*)(Vh + k + 4);
    f32x4 v1a = *(const f32x4*)(Vh + K_TOT + k);
    f32x4 v1b = *(const f32x4*)(Vh + K_TOT + k + 4);
    u16x8 hi;
#pragma unroll
    for (int q = 0; q < 4; ++q) {
      unsigned short h = f2bf(x0[q]); hi[q] = h;
      float r = x0[q] - bf2f(h);
      t0 += r * v0a[q]; t1 += r * v1a[q];
    }
#pragma unroll
    for (int q = 0; q < 4; ++q) {
      unsigned short h = f2bf(x1[q]); hi[4 + q] = h;
      float r = x1[q] - bf2f(h);
      t0 += r * v0b[q]; t1 += r * v1b[q];
    }
    size_t tile = (size_t)((m >> 8) * 64 + (c >> 2)) * 16384;  // bytes
    *(u16x8*)((char*)Xhi_t + tile + swz_byte(m & 255, c & 3)) = hi;
  }
#pragma unroll
  for (int d = 32; d; d >>= 1) {
    t0 += __shfl_xor(t0, d, 64);
    t1 += __shfl_xor(t1, d, 64);
  }
  if (lane == 0) { T[2 * m] = t0; T[2 * m + 1] = t1; }
}

// 2-product GEMM: out = x_hi*(w_hi + w_lo)^T + bias + rank2(T,CU)
// BM=256 BN=128 BK=32, 4 waves (2x2), wave tile 128x64, acc[8][4].
__global__ __launch_bounds__(256, 2) void gemm2_kernel(
    const unsigned short* __restrict__ Xhi_t, const unsigned short* __restrict__ Whi_t,
    const unsigned short* __restrict__ Wlo_t, const float* __restrict__ bias,
    const float* __restrict__ T, const float* __restrict__ CU,
    float* __restrict__ out) {
  __shared__ unsigned short sA[8192];   // 16 KB (swizzled image)
  __shared__ unsigned short sBh[4096];  // 8 KB
  __shared__ unsigned short sBl[4096];  // 8 KB

  const int tid = threadIdx.x;
  const int lane = tid & 63;
  const int w = tid >> 6;
  const int wr = w >> 1, wc = w & 1;      // wave -> 128x64 sub-tile
  const int r = lane & 15, g = lane >> 4; // MFMA fragment coords
  // bijective XCD swizzle: 1024 blocks, 8 XCDs
  const int bid = blockIdx.x;
  const int x = ((bid & 7) << 7) | (bid >> 3);
  const int bn = x & 15, bm = x >> 4;

  f32x4 acc[8][4] = {};

  const unsigned short* Asrc  = Xhi_t + (size_t)bm * 64 * 8192;  // elements
  const unsigned short* Bhsrc = Whi_t + (size_t)bn * 64 * 4096;
  const unsigned short* Blsrc = Wlo_t + (size_t)bn * 64 * 4096;
  const int sw = (r & 7) << 4;

  for (int kt = 0; kt < 64; ++kt) {
    __syncthreads();  // all waves done reading previous tile
    // stage A: 16 chunks x 1KB; wave w -> chunks 4w..4w+3
#pragma unroll
    for (int ii = 0; ii < 4; ++ii) {
      int ch = (w << 2) + ii;
      __builtin_amdgcn_global_load_lds(
          (const __attribute__((address_space(1))) void*)(Asrc + (size_t)kt * 8192 + ch * 512 + lane * 8),
          (__attribute__((address_space(3))) void*)(&sA[ch * 512]), 16, 0, 0);
    }
    // stage B hi/lo: 8 chunks each; wave w -> chunks 2w, 2w+1
#pragma unroll
    for (int ii = 0; ii < 2; ++ii) {
      int ch = (w << 1) + ii;
      __builtin_amdgcn_global_load_lds(
          (const __attribute__((address_space(1))) void*)(Bhsrc + (size_t)kt * 4096 + ch * 512 + lane * 8),
          (__attribute__((address_space(3))) void*)(&sBh[ch * 512]), 16, 0, 0);
      __builtin_amdgcn_global_load_lds(
          (const __attribute__((address_space(1))) void*)(Blsrc + (size_t)kt * 4096 + ch * 512 + lane * 8),
          (__attribute__((address_space(3))) void*)(&sBl[ch * 512]), 16, 0, 0);
    }
    __syncthreads();  // compiler drains vmcnt(0) before barrier -> tile ready

    short8 bh[4], bl[4];
#pragma unroll
    for (int j = 0; j < 4; ++j) {
      int bb = (((wc << 6) + (j << 4) + r) << 6) + (g << 4);
      bb ^= sw;
      bh[j] = *(const short8*)((const char*)sBh + bb);
      bl[j] = *(const short8*)((const char*)sBl + bb);
    }
#pragma unroll
    for (int i = 0; i < 8; ++i) {
      int ab = (((wr << 7) + (i << 4) + r) << 6) + (g << 4);
      ab ^= sw;
      short8 a = *(const short8*)((const char*)sA + ab);
#pragma unroll
      for (int j = 0; j < 4; ++j) {
        acc[i][j] = __builtin_amdgcn_mfma_f32_16x16x32_bf16(a, bh[j], acc[i][j], 0, 0, 0);
        acc[i][j] = __builtin_amdgcn_mfma_f32_16x16x32_bf16(a, bl[j], acc[i][j], 0, 0, 0);
      }
    }
  }

  // epilogue: C/D col = lane&15 (n), row = (lane>>4)*4+reg (m)  [m89-verified]
  float bv[4], cu0[4], cu1[4];
  int nn[4];
#pragma unroll
  for (int j = 0; j < 4; ++j) {
    int n = (bn << 7) + (wc << 6) + (j << 4) + r;
    nn[j] = n;
    bv[j] = bias[n];
    f32x2 cu = *(const f32x2*)(CU + 2 * n);
    cu0[j] = cu.x; cu1[j] = cu.y;
  }
#pragma unroll
  for (int i = 0; i < 8; ++i) {
#pragma unroll
    for (int q = 0; q < 4; ++q) {
      int m = (bm << 8) + (wr << 7) + (i << 4) + (g << 2) + q;
      f32x2 tv = *(const f32x2*)(T + 2 * m);
      float* orow = out + (size_t)m * N_TOT;
#pragma unroll
      for (int j = 0; j < 4; ++j) {
        orow[nn[j]] = acc[i][j][q] + bv[j] + tv.x * cu0[j] + tv.y * cu1[j];
      }
    }
  }
}

// ===================== FALLBACK PATH (round-1, proven) ======================
__global__ void wsplit_kernel(const float* __restrict__ Wb, const float* __restrict__ U,
                              const float* __restrict__ S, const float* __restrict__ Vh,
                              const float* __restrict__ P, const float* __restrict__ gv,
                              unsigned short* __restrict__ Whi, unsigned short* __restrict__ Wlo) {
  float c0 = 0.f, c1 = 0.f;
#pragma unroll
  for (int u = 0; u < 16; ++u) { c0 += gv[u] * P[2 * u]; c1 += gv[u] * P[2 * u + 1]; }
  c0 *= S[0]; c1 *= S[1];
  int t = blockIdx.x * 256 + threadIdx.x;
  int o = t >> 9;
  int d = (t & 511) << 2;
  f32x4 wb = *(const f32x4*)(Wb + (size_t)o * K_TOT + d);
  f32x4 v0 = *(const f32x4*)(Vh + d);
  f32x4 v1 = *(const f32x4*)(Vh + K_TOT + d);
  float u0 = U[2 * o] * c0, u1 = U[2 * o + 1] * c1;
  u16x4 hi, lo;
#pragma unroll
  for (int q = 0; q < 4; ++q) {
    float w = wb[q] + u0 * v0[q] + u1 * v1[q];
    unsigned short h = f2bf(w);
    hi[q] = h;
    lo[q] = f2bf(w - bf2f(h));
  }
  *(u16x4*)(Whi + (size_t)o * K_TOT + d) = hi;
  *(u16x4*)(Wlo + (size_t)o * K_TOT + d) = lo;
}

__global__ __launch_bounds__(256) void gemm_split_kernel(
    const float* __restrict__ X, const unsigned short* __restrict__ Whi,
    const unsigned short* __restrict__ Wlo, const float* __restrict__ bias,
    float* __restrict__ out) {
  __shared__ unsigned short sAhi[128 * 32];
  __shared__ unsigned short sAlo[128 * 32];
  __shared__ unsigned short sBhi[128 * 32];
  __shared__ unsigned short sBlo[128 * 32];
  const int tid = threadIdx.x;
  const int lane = tid & 63;
  const int w = tid >> 6;
  const int wr = w >> 1, wc = w & 1;
  const int r = lane & 15, g = lane >> 4;
  const int bn = blockIdx.x, bm = blockIdx.y;
  f32x4 acc[4][4] = {};
  const int arow = tid >> 3;
  const int acol = (tid & 7) << 2;
  const float* Abase = X + (size_t)(bm * 128 + arow) * K_TOT + acol;
  const int brow = lane >> 2;
  const int bcol = (lane & 3) << 3;
  const size_t bgoff = (size_t)(bn * 128 + brow) * K_TOT + bcol;
  for (int kt = 0; kt < K_TOT / 32; ++kt) {
    f32x4 av[4];
#pragma unroll
    for (int p = 0; p < 4; ++p)
      av[p] = *(const f32x4*)(Abase + (size_t)(p * 32) * K_TOT + kt * 32);
    __syncthreads();
#pragma unroll
    for (int ii = 0; ii < 2; ++ii) {
      int chunk = w * 2 + ii;
      size_t go = bgoff + (size_t)(chunk * 16) * K_TOT + kt * 32;
      __builtin_amdgcn_global_load_lds(
          (const __attribute__((address_space(1))) void*)(Whi + go),
          (__attribute__((address_space(3))) void*)(&sBhi[chunk * 512]), 16, 0, 0);
      __builtin_amdgcn_global_load_lds(
          (const __attribute__((address_space(1))) void*)(Wlo + go),
          (__attribute__((address_space(3))) void*)(&sBlo[chunk * 512]), 16, 0, 0);
    }
#pragma unroll
    for (int p = 0; p < 4; ++p) {
      u16x4 hi, lo;
#pragma unroll
      for (int q = 0; q < 4; ++q) {
        float f = av[p][q];
        unsigned short h = f2bf(f);
        hi[q] = h;
        lo[q] = f2bf(f - bf2f(h));
      }
      int off = (arow + p * 32) * 32 + acol;
      *(u16x4*)&sAhi[off] = hi;
      *(u16x4*)&sAlo[off] = lo;
    }
    __syncthreads();
    short8 ah[4], al[4], bh[4], bl[4];
#pragma unroll
    for (int i = 0; i < 4; ++i) {
      int off = (wr * 64 + i * 16 + r) * 32 + g * 8;
      ah[i] = *(const short8*)&sAhi[off];
      al[i] = *(const short8*)&sAlo[off];
    }
#pragma unroll
    for (int j = 0; j < 4; ++j) {
      int off = (wc * 64 + j * 16 + r) * 32 + g * 8;
      bh[j] = *(const short8*)&sBhi[off];
      bl[j] = *(const short8*)&sBlo[off];
    }
#pragma unroll
    for (int i = 0; i < 4; ++i)
#pragma unroll
      for (int j = 0; j < 4; ++j) {
        acc[i][j] = __builtin_amdgcn_mfma_f32_16x16x32_bf16(ah[i], bh[j], acc[i][j], 0, 0, 0);
        acc[i][j] = __builtin_amdgcn_mfma_f32_16x16x32_bf16(ah[i], bl[j], acc[i][j], 0, 0, 0);
        acc[i][j] = __builtin_amdgcn_mfma_f32_16x16x32_bf16(al[i], bh[j], acc[i][j], 0, 0, 0);
      }
  }
#pragma unroll
  for (int j = 0; j < 4; ++j) {
    int n = bn * 128 + wc * 64 + j * 16 + r;
    float bvv = bias[n];
#pragma unroll
    for (int i = 0; i < 4; ++i) {
      int mbase = bm * 128 + wr * 64 + i * 16 + g * 4;
#pragma unroll
      for (int q = 0; q < 4; ++q) {
        out[(size_t)(mbase + q) * N_TOT + n] = acc[i][j][q] + bvv;
      }
    }
  }
}

// ===========================================================================
extern "C" void kernel_launch(void* const* d_in, const int* in_sizes, int n_in,
                              void* d_out, int out_size, void* d_ws, size_t ws_size,
                              hipStream_t stream) {
  const float* x    = (const float*)d_in[0];
  const float* Wb   = (const float*)d_in[1];
  const float* bias = (const float*)d_in[2];
  const float* U    = (const float*)d_in[3];
  const float* S    = (const float*)d_in[4];
  const float* Vh   = (const float*)d_in[5];
  const float* P    = (const float*)d_in[6];
  const float* gv   = (const float*)d_in[7];
  float* out = (float*)d_out;

  const size_t W_ELE = (size_t)N_TOT * K_TOT;   // 4,194,304
  const size_t X_ELE = (size_t)M_TOT * K_TOT;   // 33,554,432
  const size_t TILED_WS = (2 * W_ELE + X_ELE) * 2 + (2 * M_TOT + 2 * N_TOT) * 4;

  if (ws_size >= TILED_WS) {
    unsigned short* Whi_t = (unsigned short*)d_ws;
    unsigned short* Wlo_t = Whi_t + W_ELE;
    unsigned short* Xhi_t = Wlo_t + W_ELE;
    float* T  = (float*)(Xhi_t + X_ELE);
    float* CU = T + 2 * M_TOT;

    wsplit_tiled<<<dim3(N_TOT), 256, 0, stream>>>(Wb, U, S, Vh, P, gv, Whi_t, Wlo_t, CU);
    xsplit_tiled<<<dim3(M_TOT / 4), 256, 0, stream>>>(x, Vh, Xhi_t, T);
    gemm2_kernel<<<dim3((M_TOT / 256) * (N_TOT / 128)), 256, 0, stream>>>(
        Xhi_t, Whi_t, Wlo_t, bias, T, CU, out);
  } else {
    unsigned short* Whi = (unsigned short*)d_ws;
    unsigned short* Wlo = Whi + W_ELE;
    wsplit_kernel<<<dim3((N_TOT * K_TOT / 4) / 256), 256, 0, stream>>>(
        Wb, U, S, Vh, P, gv, Whi, Wlo);
    gemm_split_kernel<<<dim3(N_TOT / 128, M_TOT / 128), 256, 0, stream>>>(
        x, Whi, Wlo, bias, out);
  }
}